// Round 2
// baseline (7365.302 us; speedup 1.0000x reference)
//
#include <hip/hip_runtime.h>
#include <stdint.h>

#define SLEN  512
#define IDIM  256
#define HDIM  512
#define NROW  256          // 2 sequences x 128 batch rows
#define KDIM  768          // IDIM + HDIM
#define KP    776          // padded LDS row stride in elements (768 + 8)
#define NB    8            // batch groups (32 rows each)
#define NC    32           // column groups (16 H-cols each)
#define NSTEP 512

typedef __attribute__((ext_vector_type(8))) _Float16 half8;
typedef __attribute__((ext_vector_type(4))) float   f32x4;
typedef unsigned short ushort_t;

__device__ __forceinline__ float sigm(float x)   { return 1.0f / (1.0f + __expf(-x)); }
__device__ __forceinline__ float tanh_f(float x) { return 2.0f / (1.0f + __expf(-2.0f * x)) - 1.0f; }

// Persistent LSTM kernel, fp32 inputs, f16 MFMA compute, fp32 cell/gate math.
// Partition: 256 WGs = 8 batch groups (blockIdx&7 -> XCD round-robin) x 32 column groups.
// Each WG: 32 batch rows x 16 H-cols (64 gate cols). W slice resident in LDS (f16),
// per-wave W A-frags cached in registers. Transposed GEMM so each lane's 4 acc regs
// are gates (i,f,g,o) for one (row, H-col): cell update is fully lane-local.
__global__ __launch_bounds__(256, 1)
void lstm_persistent(const float* __restrict__ x0, const float* __restrict__ x1,
                     const float* __restrict__ wih, const float* __restrict__ whh,
                     const float* __restrict__ bih, const float* __restrict__ bhh,
                     _Float16* __restrict__ hb, int* __restrict__ cnt,
                     float* __restrict__ out) {
    extern __shared__ _Float16 smem[];
    _Float16* Wl = smem;            // [64][KP] arranged W rows (f16)
    _Float16* Ab = smem + 64 * KP;  // [32][KP] activations [x_t | h_{t-1}] (f16)

    const int tid  = threadIdx.x;
    const int lane = tid & 63;
    const int w    = tid >> 6;      // wave 0..3
    const int quad = lane >> 4;
    const int l16  = lane & 15;
    const int igrp = blockIdx.x & 7;    // batch group
    const int jcg  = blockIdx.x >> 3;   // column group 0..31

    // ---- load arranged W slice into LDS once (fp32 global -> f16 LDS) ----
    // arranged row a = mt*16 + (ccl*4 + q); content = [W_ih[gc][0:256) | W_hh[gc][0:512)]
    // gc = q*512 + jcg*16 + mt*4 + ccl   (q = gate i/f/g/o)
    for (int p = 0; p < 24; ++p) {
        int c  = tid + p * 256;      // 0..6143 chunks of 8 elements
        int a  = c / 96;
        int ck = c - a * 96;
        int k0 = ck * 8;
        int r  = a & 15, mt = a >> 4;
        int q  = r & 3,  ccl = r >> 2;
        int gc = q * HDIM + jcg * 16 + mt * 4 + ccl;
        const float* src = (k0 < IDIM) ? (wih + (size_t)gc * IDIM + k0)
                                       : (whh + (size_t)gc * HDIM + (k0 - IDIM));
        float4 f0 = *(const float4*)(src);
        float4 f1 = *(const float4*)(src + 4);
        half8 v;
        v[0] = (_Float16)f0.x; v[1] = (_Float16)f0.y; v[2] = (_Float16)f0.z; v[3] = (_Float16)f0.w;
        v[4] = (_Float16)f1.x; v[5] = (_Float16)f1.y; v[6] = (_Float16)f1.z; v[7] = (_Float16)f1.w;
        *(half8*)&Wl[a * KP + k0] = v;
    }
    __syncthreads();

    // ---- per-wave tiles: nt = N-tile (batch rows), mtb..mtb+1 = M-tiles (gate cols) ----
    const int nt  = w & 1;
    const int mtb = (w >> 1) * 2;

    // ---- preload W A-frags into registers (step-invariant): A[m=lane&15][k=quad*8+j] ----
    half8 wf0[24], wf1[24];
#pragma unroll
    for (int kk = 0; kk < 24; ++kk) {
        wf0[kk] = *(const half8*)&Wl[(mtb * 16 + l16) * KP + kk * 32 + quad * 8];
        wf1[kk] = *(const half8*)&Wl[((mtb + 1) * 16 + l16) * KP + kk * 32 + quad * 8];
    }

    // ---- bias preload (fp32): C-frag m = quad*4 + reg -> reg q is gate q at H-col (mt*4+quad)
    float bias0[4], bias1[4];
#pragma unroll
    for (int q = 0; q < 4; ++q) {
        int g0 = q * HDIM + jcg * 16 + (mtb + 0) * 4 + quad;
        int g1 = q * HDIM + jcg * 16 + (mtb + 1) * 4 + quad;
        bias0[q] = bih[g0] + bhh[g0];
        bias1[q] = bih[g1] + bhh[g1];
    }

    float c0 = 0.f, c1 = 0.f;     // cell state, lane-local, fp32
    int gaveup = 0;               // spin-timeout failsafe (prevents harness hang)
    const int grow_me = igrp * 32 + nt * 16 + l16;                 // my batch row
    const int cc0 = jcg * 16 + (mtb + 0) * 4 + quad;               // my H-cols
    const int cc1 = jcg * 16 + (mtb + 1) * 4 + quad;

#pragma unroll 1
    for (int t = 0; t < NSTEP; ++t) {
        // wait for h_{t-1} from all 32 WGs of this batch group
        if (t > 0 && tid == 0 && !gaveup) {
            int idx = igrp * NSTEP + (t - 1);
            int it = 0;
            while (__hip_atomic_load(&cnt[idx], __ATOMIC_RELAXED, __HIP_MEMORY_SCOPE_AGENT) < NC) {
                __builtin_amdgcn_s_sleep(2);
                if (++it > (1 << 22)) { gaveup = 1; break; }
            }
            (void)__hip_atomic_load(&cnt[idx], __ATOMIC_ACQUIRE, __HIP_MEMORY_SCOPE_AGENT);
        }
        __syncthreads();   // h ready + prev-step GEMM reads of Ab done

        // ---- stage x_t (32 rows x 256, fp32 -> f16) ----
        {
            const float* xp = (igrp < 4) ? x0 : x1;
            int bbase = (igrp * 32) & 127;
#pragma unroll
            for (int p = 0; p < 4; ++p) {
                int c = tid + p * 256;          // 1024 chunks of 8
                int row = c >> 5;
                int o8 = (c & 31) * 8;
                const float* src = xp + ((size_t)(bbase + row) * SLEN + t) * IDIM + o8;
                float4 f0 = *(const float4*)(src);
                float4 f1 = *(const float4*)(src + 4);
                half8 v;
                v[0] = (_Float16)f0.x; v[1] = (_Float16)f0.y; v[2] = (_Float16)f0.z; v[3] = (_Float16)f0.w;
                v[4] = (_Float16)f1.x; v[5] = (_Float16)f1.y; v[6] = (_Float16)f1.z; v[7] = (_Float16)f1.w;
                *(half8*)&Ab[row * KP + o8] = v;
            }
            // ---- stage h_{t-1} (32 rows x 512, already f16) from ping-pong buffer ----
            const _Float16* hs = hb + (size_t)((t + 1) & 1) * (NROW * HDIM);
#pragma unroll
            for (int p = 0; p < 8; ++p) {
                int c = tid + p * 256;          // 2048 chunks of 8
                int row = c >> 6;
                int o8 = (c & 63) * 8;
                half8 v = *(const half8*)(hs + (size_t)(igrp * 32 + row) * HDIM + o8);
                *(half8*)&Ab[row * KP + IDIM + o8] = v;
            }
        }
        __syncthreads();

        // ---- GEMM: D[m=gatecol][n=row] = sum_k W_arr[m][k] * Act[n][k], fp32 acc = bias ----
        f32x4 acc0 = {bias0[0], bias0[1], bias0[2], bias0[3]};
        f32x4 acc1 = {bias1[0], bias1[1], bias1[2], bias1[3]};
        const _Float16* abase = &Ab[(nt * 16 + l16) * KP + quad * 8];
#pragma unroll
        for (int kk = 0; kk < 24; ++kk) {
            half8 bf = *(const half8*)(abase + kk * 32);
            acc0 = __builtin_amdgcn_mfma_f32_16x16x32_f16(wf0[kk], bf, acc0, 0, 0, 0);
            acc1 = __builtin_amdgcn_mfma_f32_16x16x32_f16(wf1[kk], bf, acc1, 0, 0, 0);
        }

        // ---- cell update (regs 0..3 = i,f,g,o), all fp32 ----
        float i0 = sigm(acc0[0]), f0 = sigm(acc0[1]), g0 = tanh_f(acc0[2]), o0 = sigm(acc0[3]);
        c0 = f0 * c0 + i0 * g0;
        float h0 = o0 * tanh_f(c0);
        float i1 = sigm(acc1[0]), f1 = sigm(acc1[1]), g1 = tanh_f(acc1[2]), o1 = sigm(acc1[3]);
        c1 = f1 * c1 + i1 * g1;
        float h1 = o1 * tanh_f(c1);

        if (t < NSTEP - 1) {
            _Float16* hd = hb + (size_t)(t & 1) * (NROW * HDIM) + (size_t)grow_me * HDIM;
            hd[cc0] = (_Float16)h0;
            hd[cc1] = (_Float16)h1;
            __syncthreads();   // all waves' h stores drained (vmcnt(0) before s_barrier)
            if (tid == 0) {
                // agent-scope release: L2 writeback so the whole group sees h_t
                __hip_atomic_fetch_add(&cnt[igrp * NSTEP + t], 1,
                                       __ATOMIC_RELEASE, __HIP_MEMORY_SCOPE_AGENT);
            }
        } else {
            // final hidden state -> output (concat layout == row-major [256][512] fp32)
            out[(size_t)grow_me * HDIM + cc0] = h0;
            out[(size_t)grow_me * HDIM + cc1] = h1;
        }
    }
}

extern "C" void kernel_launch(void* const* d_in, const int* in_sizes, int n_in,
                              void* d_out, int out_size, void* d_ws, size_t ws_size,
                              hipStream_t stream) {
    const float* x0  = (const float*)d_in[0];   // text_one [128,512,256] fp32
    const float* x1  = (const float*)d_in[1];   // text_two
    const float* wih = (const float*)d_in[2];   // [2048,256]
    const float* whh = (const float*)d_in[3];   // [2048,512]
    const float* bih = (const float*)d_in[4];   // [2048]
    const float* bhh = (const float*)d_in[5];   // [2048]

    // ws layout: h ping-pong (2 x 256KB f16) + per-(group,step) arrival counters
    _Float16* hb = (_Float16*)d_ws;
    int* cnt = (int*)((char*)d_ws + (size_t)2 * NROW * HDIM * sizeof(_Float16));
    size_t zbytes = (size_t)2 * NROW * HDIM * sizeof(_Float16) + (size_t)NB * NSTEP * sizeof(int);
    hipMemsetAsync(d_ws, 0, zbytes, stream);   // zero h_{-1} + counters (ws is 0xAA-poisoned)

    const int smem_bytes = 96 * KP * (int)sizeof(_Float16);  // 148,992 B -> 1 WG/CU
    hipFuncSetAttribute((const void*)lstm_persistent,
                        hipFuncAttributeMaxDynamicSharedMemorySize, smem_bytes);

    lstm_persistent<<<dim3(256), dim3(256), smem_bytes, stream>>>(
        x0, x1, wih, whh, bih, bhh, hb, cnt, (float*)d_out);
}